// Round 7
// baseline (8570.303 us; speedup 1.0000x reference)
//
#include <hip/hip_runtime.h>
#include <hip/hip_bf16.h>

#define N_DIM 1024
#define R_DIM 6
#define B_DIM 64
#define T_DIM 400
#define NBLK 16
#define WPB  16   // waves per block

typedef short bf16x8 __attribute__((ext_vector_type(8)));
typedef float f32x4 __attribute__((ext_vector_type(4)));
typedef unsigned u32x4 __attribute__((ext_vector_type(4)));

__device__ inline unsigned short f2bf(float f) {
    unsigned int u = __float_as_uint(f);
    unsigned int r = (u + 0x7fffu + ((u >> 16) & 1u)) >> 16;
    return (unsigned short)r;
}

// Build W in MFMA B-fragment layout, bf16.
// WF[gg][s][lane][i] = W[16gg + (lane&15)][32s + (lane>>4)*8 + i]
// Block 0 zeroes the 256 packed wave flags.
__global__ void __launch_bounds__(64) build_wf(
    const float* __restrict__ lv,
    const float* __restrict__ rv,
    const float* __restrict__ noise,
    unsigned short* __restrict__ wf,
    unsigned* __restrict__ flags)
{
    int blk = blockIdx.x;
    int l = threadIdx.x;
    if (blk == 0) {
        flags[l * 4 + 0] = 0u; flags[l * 4 + 1] = 0u;
        flags[l * 4 + 2] = 0u; flags[l * 4 + 3] = 0u;
    }
    int gg = blk >> 5;
    int s = blk & 31;
    int j = gg * 16 + (l & 15);
    int n0 = s * 32 + (l >> 4) * 8;
    unsigned short* dst = wf + ((size_t)blk * 64 + l) * 8;
    float rj[R_DIM];
#pragma unroll
    for (int k = 0; k < R_DIM; ++k) rj[k] = rv[k * N_DIM + j];
#pragma unroll
    for (int i = 0; i < 8; ++i) {
        int n = n0 + i;
        float acc = noise[j * N_DIM + n];
        float dot = 0.f;
#pragma unroll
        for (int k = 0; k < R_DIM; ++k) dot += rj[k] * lv[k * N_DIM + n];
        acc += dot * (1.0f / (float)N_DIM);
        dst[i] = f2bf(acc);
    }
}

// Publish a[4] (rows brow0..brow0+3, col jcol): full-wave, non-atomic,
// write-through (sc0 sc1). Pair transpose as in R6 (verified).
__device__ inline void publish_a(unsigned short* dst, const float a[4],
                                 int brow0, int jcol, int l) {
    unsigned* d32 = (unsigned*)dst;
    int odd = l & 1;
    int j0 = jcol & ~1;
#pragma unroll
    for (int k = 0; k < 2; ++k) {
        float send = odd ? a[k] : a[k + 2];
        float got = __shfl_xor(send, 1);
        int row = brow0 + (odd ? (k + 2) : k);
        unsigned lo = odd ? f2bf(got)     : f2bf(a[k]);      // col j0
        unsigned hi = odd ? f2bf(a[k + 2]) : f2bf(got);      // col j0+1
        unsigned pk = lo | (hi << 16);
        unsigned* addr = d32 + ((row * N_DIM + j0) >> 1);
        asm volatile("global_store_dword %0, %1, off sc0 sc1"
                     :: "v"(addr), "v"(pk) : "memory");
    }
}

// Every wave polls all 256 packed wave-flags: one dwordx4 per lane per sweep.
__device__ inline void poll_all(const unsigned* flags, unsigned target, int l) {
    const u32x4* fp = (const u32x4*)flags + l;
    for (;;) {
        u32x4 v;
        asm volatile("global_load_dwordx4 %0, %1, off sc0 sc1\n\t"
                     "s_waitcnt vmcnt(0)"
                     : "=v"(v) : "v"(fp) : "memory");
        unsigned a = v.x < v.y ? v.x : v.y;
        unsigned b = v.z < v.w ? v.z : v.w;
        unsigned m = a < b ? a : b;
        if (__all(m >= target)) break;
        __builtin_amdgcn_s_sleep(1);
    }
}

// Coherent 16B load into register bank slot.
#define LOADA(slot, off)                                                       \
    asm volatile("global_load_dwordx4 %0, %1, off offset:" #off " sc0 sc1"     \
                 : "=v"(av[slot]) : "v"(ap) : "memory");

#define MFMA4(bank, sbase)                                                     \
    acc0 = __builtin_amdgcn_mfma_f32_16x16x32_bf16(av[(bank) * 8 + 0], wfrag[wbase + ((sbase) + 0) * 64 + l], acc0, 0, 0, 0); \
    acc1 = __builtin_amdgcn_mfma_f32_16x16x32_bf16(av[(bank) * 8 + 1], wfrag[wbase + ((sbase) + 1) * 64 + l], acc1, 0, 0, 0); \
    acc2 = __builtin_amdgcn_mfma_f32_16x16x32_bf16(av[(bank) * 8 + 2], wfrag[wbase + ((sbase) + 2) * 64 + l], acc2, 0, 0, 0); \
    acc3 = __builtin_amdgcn_mfma_f32_16x16x32_bf16(av[(bank) * 8 + 3], wfrag[wbase + ((sbase) + 3) * 64 + l], acc3, 0, 0, 0); \
    acc0 = __builtin_amdgcn_mfma_f32_16x16x32_bf16(av[(bank) * 8 + 4], wfrag[wbase + ((sbase) + 4) * 64 + l], acc0, 0, 0, 0); \
    acc1 = __builtin_amdgcn_mfma_f32_16x16x32_bf16(av[(bank) * 8 + 5], wfrag[wbase + ((sbase) + 5) * 64 + l], acc1, 0, 0, 0); \
    acc2 = __builtin_amdgcn_mfma_f32_16x16x32_bf16(av[(bank) * 8 + 6], wfrag[wbase + ((sbase) + 6) * 64 + l], acc2, 0, 0, 0); \
    acc3 = __builtin_amdgcn_mfma_f32_16x16x32_bf16(av[(bank) * 8 + 7], wfrag[wbase + ((sbase) + 7) * 64 + l], acc3, 0, 0, 0);

// 16 blocks x 1024 threads (cooperative; 4 waves/SIMD for TLP).
// Block g owns j-cols [64g, 64g+64); wave w=(wr,wc): wr=batch band (16 rows),
// wc=jcol sub-band (16 cols). Per-wave flags, zero barriers in the T-loop.
__global__ void __launch_bounds__(1024, 4) rnn_recurrence(
    const float* __restrict__ hidden0,
    const float* __restrict__ input,        // [B][T][N]
    const unsigned short* __restrict__ wf,
    float* __restrict__ out_hidden,         // [T][B][N]
    unsigned short* __restrict__ abuf0,
    unsigned short* __restrict__ abuf1,
    unsigned* __restrict__ flags)
{
    const int g = blockIdx.x;
    const int tid = threadIdx.x;
    const int w = tid >> 6;          // 0..15
    const int l = tid & 63;
    const int wr = w >> 2;           // batch band
    const int wc = w & 3;            // jcol sub-band
    const int jcol = g * 64 + wc * 16 + (l & 15);
    const int brow0 = wr * 16 + (l >> 4) * 4;
    const int wid = g * WPB + w;     // 0..255

    // ---- stage this block's W slice (64 jcols = 128 KB) into LDS ----
    extern __shared__ unsigned short wlds[];
    {
        const bf16x8* src = reinterpret_cast<const bf16x8*>(wf) + (size_t)g * 8192;
        bf16x8* dstl = reinterpret_cast<bf16x8*>(wlds);
#pragma unroll
        for (int i = 0; i < 8; ++i)
            dstl[tid + i * 1024] = src[tid + i * 1024];
    }
    __syncthreads();
    const bf16x8* wfrag = reinterpret_cast<const bf16x8*>(wlds);
    const int wbase = wc * 2048;     // wc*32 frags * 64 lanes

    // ---- init h-state & publish a0, set own flag ----
    float h0v = hidden0[jcol];
    float h[4];
#pragma unroll
    for (int i = 0; i < 4; ++i) h[i] = h0v;
    {
        float a0[4];
#pragma unroll
        for (int i = 0; i < 4; ++i) a0[i] = tanhf(h0v);
        publish_a(abuf0, a0, brow0, jcol, l);
        asm volatile("s_waitcnt vmcnt(0)" ::: "memory");
        if (l == 0) {
            unsigned one = 1u;
            asm volatile("global_store_dword %0, %1, off sc0 sc1"
                         :: "v"(flags + wid), "v"(one) : "memory");
        }
    }

    const int aoff_us = (wr * 16 + (l & 15)) * N_DIM + (l >> 4) * 8;

    for (int t = 0; t < T_DIM; ++t) {
        const unsigned short* acur = (t & 1) ? abuf1 : abuf0;
        unsigned short* anext = (t & 1) ? abuf0 : abuf1;
        const unsigned short* ap = acur + aoff_us;

        // x loads issued before the poll (HBM latency hides under the wait)
        float x[4];
#pragma unroll
        for (int i = 0; i < 4; ++i)
            x[i] = input[((size_t)(brow0 + i) * T_DIM + t) * N_DIM + jcol];

        // wait until all 256 waves have published a_t
        poll_all(flags, (unsigned)(t + 1), l);

        // ---- a-loads: 2 banks x 8, pipelined (TLP hides exposure) ----
        bf16x8 av[16];
        LOADA(0, 0)    LOADA(1, 64)   LOADA(2, 128)  LOADA(3, 192)
        LOADA(4, 256)  LOADA(5, 320)  LOADA(6, 384)  LOADA(7, 448)
        LOADA(8, 512)  LOADA(9, 576)  LOADA(10, 640) LOADA(11, 704)
        LOADA(12, 768) LOADA(13, 832) LOADA(14, 896) LOADA(15, 960)

        f32x4 acc0 = {0.f, 0.f, 0.f, 0.f};
        f32x4 acc1 = {0.f, 0.f, 0.f, 0.f};
        f32x4 acc2 = {0.f, 0.f, 0.f, 0.f};
        f32x4 acc3 = {0.f, 0.f, 0.f, 0.f};

        asm volatile("s_waitcnt vmcnt(8)" ::: "memory");   // G0 done
        __builtin_amdgcn_sched_barrier(0);
        MFMA4(0, 0)
        LOADA(0, 1024) LOADA(1, 1088) LOADA(2, 1152) LOADA(3, 1216)
        LOADA(4, 1280) LOADA(5, 1344) LOADA(6, 1408) LOADA(7, 1472)
        asm volatile("s_waitcnt vmcnt(8)" ::: "memory");   // G1 done
        __builtin_amdgcn_sched_barrier(0);
        MFMA4(1, 8)
        LOADA(8, 1536)  LOADA(9, 1600)  LOADA(10, 1664) LOADA(11, 1728)
        LOADA(12, 1792) LOADA(13, 1856) LOADA(14, 1920) LOADA(15, 1984)
        asm volatile("s_waitcnt vmcnt(8)" ::: "memory");   // G2 done
        __builtin_amdgcn_sched_barrier(0);
        MFMA4(0, 16)
        asm volatile("s_waitcnt vmcnt(0)" ::: "memory");   // G3 done
        __builtin_amdgcn_sched_barrier(0);
        MFMA4(1, 24)

        f32x4 acc = (acc0 + acc1) + (acc2 + acc3);

        // ---- h update + activation ----
        float a[4];
#pragma unroll
        for (int i = 0; i < 4; ++i) {
            float hn = 0.9f * h[i] + 0.1f * (acc[i] + x[i]);
            h[i] = hn;
            a[i] = tanhf(hn);
        }

        if (t + 1 < T_DIM) {
            publish_a(anext, a, brow0, jcol, l);
            asm volatile("s_waitcnt vmcnt(0)" ::: "memory");   // publishes at MALL
            if (l == 0) {
                unsigned nf = (unsigned)(t + 2);
                asm volatile("global_store_dword %0, %1, off sc0 sc1"
                             :: "v"(flags + wid), "v"(nf) : "memory");
            }
        }
        // out_hidden stores off the critical path (after flag release)
#pragma unroll
        for (int i = 0; i < 4; ++i)
            out_hidden[((size_t)t * B_DIM + (brow0 + i)) * N_DIM + jcol] = a[i];
    }
}

__global__ void __launch_bounds__(256) geo_kernel(
    const float* __restrict__ hid,
    const float* __restrict__ gW,
    const float* __restrict__ gb,
    const float* __restrict__ rW,
    float* __restrict__ geo,
    float* __restrict__ ro)
{
    int row = blockIdx.x * 4 + (threadIdx.x >> 6);
    int l = threadIdx.x & 63;
    const float* hrow = hid + (size_t)row * N_DIM;
    float a0 = 0.f, a1 = 0.f;
#pragma unroll
    for (int i = 0; i < N_DIM / 64; ++i) {
        int idx = i * 64 + l;
        float th = tanhf(hrow[idx]);
        a0 += th * gW[idx];
        a1 += th * gW[N_DIM + idx];
    }
#pragma unroll
    for (int off = 32; off; off >>= 1) {
        a0 += __shfl_down(a0, off);
        a1 += __shfl_down(a1, off);
    }
    if (l == 0) {
        float g0 = a0 + gb[0];
        float g1 = a1 + gb[1];
        geo[(size_t)row * 2 + 0] = g0;
        geo[(size_t)row * 2 + 1] = g1;
#pragma unroll
        for (int m = 0; m < 6; ++m)
            ro[(size_t)row * 6 + m] = g0 * rW[m * 2] + g1 * rW[m * 2 + 1];
    }
}

extern "C" void kernel_launch(void* const* d_in, const int* in_sizes, int n_in,
                              void* d_out, int out_size, void* d_ws, size_t ws_size,
                              hipStream_t stream) {
    const float* hidden0 = (const float*)d_in[0];
    const float* input   = (const float*)d_in[1];
    const float* lv      = (const float*)d_in[2];
    const float* rv      = (const float*)d_in[3];
    const float* noise   = (const float*)d_in[4];
    const float* gW      = (const float*)d_in[5];
    const float* gb      = (const float*)d_in[6];
    const float* rW      = (const float*)d_in[7];

    float* out_hidden = (float*)d_out;
    float* geo = out_hidden + (size_t)T_DIM * B_DIM * N_DIM;
    float* ro  = geo + (size_t)T_DIM * B_DIM * 2;

    unsigned short* wf    = (unsigned short*)d_ws;                  // 2 MB
    unsigned short* abuf0 = wf + (size_t)64 * 32 * 64 * 8;          // 128 KB
    unsigned short* abuf1 = abuf0 + (size_t)B_DIM * N_DIM;          // 128 KB
    unsigned* flags = (unsigned*)(abuf1 + (size_t)B_DIM * N_DIM);   // 1 KB packed

    build_wf<<<2048, 64, 0, stream>>>(lv, rv, noise, wf, flags);

    void* args[] = { (void*)&hidden0, (void*)&input, (void*)&wf,
                     (void*)&out_hidden, (void*)&abuf0, (void*)&abuf1, (void*)&flags };
    hipLaunchCooperativeKernel((const void*)rnn_recurrence, dim3(NBLK), dim3(1024),
                               args, 131072, stream);

    geo_kernel<<<(T_DIM * B_DIM) / 4, 256, 0, stream>>>(out_hidden, gW, gb, rW, geo, ro);
}

// Round 9
// 2572.308 us; speedup vs baseline: 3.3318x; 3.3318x over previous
//
#include <hip/hip_runtime.h>
#include <hip/hip_bf16.h>

#define N_DIM 1024
#define R_DIM 6
#define B_DIM 64
#define T_DIM 400
#define NBLK 32

typedef short bf16x8 __attribute__((ext_vector_type(8)));
typedef float f32x4 __attribute__((ext_vector_type(4)));

__device__ inline unsigned short f2bf(float f) {
    unsigned int u = __float_as_uint(f);
    unsigned int r = (u + 0x7fffu + ((u >> 16) & 1u)) >> 16;
    return (unsigned short)r;
}

// Build W in MFMA B-fragment layout, bf16.
// WF[gg][s][lane][i] = W[16gg + (lane&15)][32s + (lane>>4)*8 + i]
// Block 0 zeroes the 128 packed wave flags (4 bands x 32 groups).
__global__ void __launch_bounds__(64) build_wf(
    const float* __restrict__ lv,
    const float* __restrict__ rv,
    const float* __restrict__ noise,
    unsigned short* __restrict__ wf,
    unsigned* __restrict__ flags)
{
    int blk = blockIdx.x;
    int l = threadIdx.x;
    if (blk == 0) { flags[l] = 0u; flags[64 + l] = 0u; }
    int gg = blk >> 5;
    int s = blk & 31;
    int j = gg * 16 + (l & 15);
    int n0 = s * 32 + (l >> 4) * 8;
    unsigned short* dst = wf + ((size_t)blk * 64 + l) * 8;
    float rj[R_DIM];
#pragma unroll
    for (int k = 0; k < R_DIM; ++k) rj[k] = rv[k * N_DIM + j];
#pragma unroll
    for (int i = 0; i < 8; ++i) {
        int n = n0 + i;
        float acc = noise[j * N_DIM + n];
        float dot = 0.f;
#pragma unroll
        for (int k = 0; k < R_DIM; ++k) dot += rj[k] * lv[k * N_DIM + n];
        acc += dot * (1.0f / (float)N_DIM);
        dst[i] = f2bf(acc);
    }
}

// Publish one 16x16 tile slice: rows brow0..brow0+3, col jcol. Full-wave,
// non-atomic, write-through (sc0 sc1). Pair transpose (verified R6/R7).
__device__ inline void publish_tile(unsigned short* dst, const float a[4],
                                    int brow0, int jcol, int l) {
    unsigned* d32 = (unsigned*)dst;
    int odd = l & 1;
    int j0 = jcol & ~1;
#pragma unroll
    for (int k = 0; k < 2; ++k) {
        float send = odd ? a[k] : a[k + 2];
        float got = __shfl_xor(send, 1);
        int row = brow0 + (odd ? (k + 2) : k);
        unsigned lo = odd ? f2bf(got)      : f2bf(a[k]);     // col j0
        unsigned hi = odd ? f2bf(a[k + 2]) : f2bf(got);      // col j0+1
        unsigned pk = lo | (hi << 16);
        unsigned* addr = d32 + ((row * N_DIM + j0) >> 1);
        asm volatile("global_store_dword %0, %1, off sc0 sc1"
                     :: "v"(addr), "v"(pk) : "memory");
    }
}

// Poll this band's 32 producer flags: 2 cachelines, broadcast lanes.
__device__ inline void poll_band(const unsigned* bandflags, unsigned target, int l) {
    const unsigned* p = bandflags + (l & 31);
    for (;;) {
        unsigned v;
        asm volatile("global_load_dword %0, %1, off sc0 sc1\n\t"
                     "s_waitcnt vmcnt(0)"
                     : "=v"(v) : "v"(p) : "memory");
        if (__all(v >= target)) break;
        __builtin_amdgcn_s_sleep(1);
    }
}

// Coherent 16B load into av slot.
#define LOADA(slot, off)                                                       \
    asm volatile("global_load_dwordx4 %0, %1, off offset:" #off " sc0 sc1"     \
                 : "=v"(av[slot]) : "v"(ap) : "memory");

// One k-chunk s: A-fragment av[s] feeds both column tiles (nt=0,1).
#define MFMA_S(s, A0, A1)                                                      \
    A0 = __builtin_amdgcn_mfma_f32_16x16x32_bf16(av[s], wfrag[(s) * 64 + l],        A0, 0, 0, 0); \
    A1 = __builtin_amdgcn_mfma_f32_16x16x32_bf16(av[s], wfrag[(32 + (s)) * 64 + l], A1, 0, 0, 0);

// 32 blocks x 256 threads (cooperative, with plain-launch fallback).
// Block g owns jcols [32g,32g+32) (W slice 64 KB static LDS, shared by its
// 4 waves). Wave w = batch band [16w,16w+16). Bands are independent chains:
// wave (g,w) waits only on the 32 waves {(g',w)} — 2 flag cachelines.
// No barriers in the T-loop.
__global__ void __launch_bounds__(256, 1) rnn_recurrence(
    const float* __restrict__ hidden0,
    const float* __restrict__ input,        // [B][T][N]
    const unsigned short* __restrict__ wf,
    float* __restrict__ out_hidden,         // [T][B][N]
    unsigned short* __restrict__ abuf0,
    unsigned short* __restrict__ abuf1,
    unsigned* __restrict__ flags)
{
    const int g = blockIdx.x;
    const int tid = threadIdx.x;
    const int w = tid >> 6;          // band
    const int l = tid & 63;
    const int brow0 = w * 16 + (l >> 4) * 4;

    // ---- stage this block's W slice (32 jcols = 64 KB) into LDS ----
    __shared__ __align__(16) unsigned short wlds[32 * 1024];
    {
        const bf16x8* src = reinterpret_cast<const bf16x8*>(wf) + (size_t)g * 4096;
        bf16x8* dstl = reinterpret_cast<bf16x8*>(wlds);
#pragma unroll
        for (int i = 0; i < 16; ++i)
            dstl[tid + i * 256] = src[tid + i * 256];
    }
    __syncthreads();
    const bf16x8* wfrag = reinterpret_cast<const bf16x8*>(wlds);

    int jc[2];
#pragma unroll
    for (int nt = 0; nt < 2; ++nt) jc[nt] = g * 32 + nt * 16 + (l & 15);

    // ---- init h & publish a0, set own flag ----
    float h[8];   // h[nt*4+i]
#pragma unroll
    for (int nt = 0; nt < 2; ++nt) {
        float h0v = hidden0[jc[nt]];
#pragma unroll
        for (int i = 0; i < 4; ++i) h[nt * 4 + i] = h0v;
    }
    {
        float a0[8];
#pragma unroll
        for (int k = 0; k < 8; ++k) a0[k] = tanhf(h[k]);
#pragma unroll
        for (int nt = 0; nt < 2; ++nt)
            publish_tile(abuf0, &a0[nt * 4], brow0, jc[nt], l);
        asm volatile("s_waitcnt vmcnt(0)" ::: "memory");
        if (l == 0) {
            unsigned one = 1u;
            asm volatile("global_store_dword %0, %1, off sc0 sc1"
                         :: "v"(flags + (w * 32 + g)), "v"(one) : "memory");
        }
    }

    const int aoff_us = (w * 16 + (l & 15)) * N_DIM + (l >> 4) * 8;
    const unsigned* bandflags = flags + w * 32;

    for (int t = 0; t < T_DIM; ++t) {
        const unsigned short* acur = (t & 1) ? abuf1 : abuf0;
        unsigned short* anext = (t & 1) ? abuf0 : abuf1;
        const unsigned short* ap = acur + aoff_us;

        // x loads issued before the poll (latency hidden under the wait)
        float x[8];
#pragma unroll
        for (int nt = 0; nt < 2; ++nt)
#pragma unroll
            for (int i = 0; i < 4; ++i)
                x[nt * 4 + i] = input[((size_t)(brow0 + i) * T_DIM + t) * N_DIM + jc[nt]];

        // wait until this band's 32 producers have published a_t
        // (poll's vmcnt(0) also drains the x loads and prior out_hidden stores)
        poll_band(bandflags, (unsigned)(t + 1), l);

        // ---- issue ALL 32 a-loads ----
        bf16x8 av[32];
        LOADA(0, 0)     LOADA(1, 64)    LOADA(2, 128)   LOADA(3, 192)
        LOADA(4, 256)   LOADA(5, 320)   LOADA(6, 384)   LOADA(7, 448)
        LOADA(8, 512)   LOADA(9, 576)   LOADA(10, 640)  LOADA(11, 704)
        LOADA(12, 768)  LOADA(13, 832)  LOADA(14, 896)  LOADA(15, 960)
        LOADA(16, 1024) LOADA(17, 1088) LOADA(18, 1152) LOADA(19, 1216)
        LOADA(20, 1280) LOADA(21, 1344) LOADA(22, 1408) LOADA(23, 1472)
        LOADA(24, 1536) LOADA(25, 1600) LOADA(26, 1664) LOADA(27, 1728)
        LOADA(28, 1792) LOADA(29, 1856) LOADA(30, 1920) LOADA(31, 1984)

        f32x4 a0e = {0.f, 0.f, 0.f, 0.f};
        f32x4 a0o = {0.f, 0.f, 0.f, 0.f};
        f32x4 a1e = {0.f, 0.f, 0.f, 0.f};
        f32x4 a1o = {0.f, 0.f, 0.f, 0.f};

        asm volatile("s_waitcnt vmcnt(24)" ::: "memory");   // a-loads 0..7 done
        __builtin_amdgcn_sched_barrier(0);
        MFMA_S(0, a0e, a1e) MFMA_S(1, a0o, a1o) MFMA_S(2, a0e, a1e) MFMA_S(3, a0o, a1o)
        MFMA_S(4, a0e, a1e) MFMA_S(5, a0o, a1o) MFMA_S(6, a0e, a1e) MFMA_S(7, a0o, a1o)
        asm volatile("s_waitcnt vmcnt(16)" ::: "memory");   // 8..15 done
        __builtin_amdgcn_sched_barrier(0);
        MFMA_S(8, a0e, a1e)  MFMA_S(9, a0o, a1o)  MFMA_S(10, a0e, a1e) MFMA_S(11, a0o, a1o)
        MFMA_S(12, a0e, a1e) MFMA_S(13, a0o, a1o) MFMA_S(14, a0e, a1e) MFMA_S(15, a0o, a1o)
        asm volatile("s_waitcnt vmcnt(8)" ::: "memory");    // 16..23 done
        __builtin_amdgcn_sched_barrier(0);
        MFMA_S(16, a0e, a1e) MFMA_S(17, a0o, a1o) MFMA_S(18, a0e, a1e) MFMA_S(19, a0o, a1o)
        MFMA_S(20, a0e, a1e) MFMA_S(21, a0o, a1o) MFMA_S(22, a0e, a1e) MFMA_S(23, a0o, a1o)
        asm volatile("s_waitcnt vmcnt(0)" ::: "memory");    // all done (incl. x)
        __builtin_amdgcn_sched_barrier(0);
        MFMA_S(24, a0e, a1e) MFMA_S(25, a0o, a1o) MFMA_S(26, a0e, a1e) MFMA_S(27, a0o, a1o)
        MFMA_S(28, a0e, a1e) MFMA_S(29, a0o, a1o) MFMA_S(30, a0e, a1e) MFMA_S(31, a0o, a1o)

        f32x4 acc0 = a0e + a0o;
        f32x4 acc1 = a1e + a1o;

        // ---- h update + activation ----
        float a[8];
#pragma unroll
        for (int i = 0; i < 4; ++i) {
            float hn;
            hn = 0.9f * h[0 + i] + 0.1f * (acc0[i] + x[0 + i]); h[0 + i] = hn; a[0 + i] = tanhf(hn);
            hn = 0.9f * h[4 + i] + 0.1f * (acc1[i] + x[4 + i]); h[4 + i] = hn; a[4 + i] = tanhf(hn);
        }

        if (t + 1 < T_DIM) {
#pragma unroll
            for (int nt = 0; nt < 2; ++nt)
                publish_tile(anext, &a[nt * 4], brow0, jc[nt], l);
            asm volatile("s_waitcnt vmcnt(0)" ::: "memory");   // publishes at MALL
            if (l == 0) {
                unsigned nf = (unsigned)(t + 2);
                asm volatile("global_store_dword %0, %1, off sc0 sc1"
                             :: "v"(flags + (w * 32 + g)), "v"(nf) : "memory");
            }
        }
        // out_hidden stores off the critical path (after flag release)
#pragma unroll
        for (int nt = 0; nt < 2; ++nt)
#pragma unroll
            for (int i = 0; i < 4; ++i)
                out_hidden[((size_t)t * B_DIM + (brow0 + i)) * N_DIM + jc[nt]] = a[nt * 4 + i];
    }
}

__global__ void __launch_bounds__(256) geo_kernel(
    const float* __restrict__ hid,
    const float* __restrict__ gW,
    const float* __restrict__ gb,
    const float* __restrict__ rW,
    float* __restrict__ geo,
    float* __restrict__ ro)
{
    int row = blockIdx.x * 4 + (threadIdx.x >> 6);
    int l = threadIdx.x & 63;
    const float* hrow = hid + (size_t)row * N_DIM;
    float a0 = 0.f, a1 = 0.f;
#pragma unroll
    for (int i = 0; i < N_DIM / 64; ++i) {
        int idx = i * 64 + l;
        float th = tanhf(hrow[idx]);
        a0 += th * gW[idx];
        a1 += th * gW[N_DIM + idx];
    }
#pragma unroll
    for (int off = 32; off; off >>= 1) {
        a0 += __shfl_down(a0, off);
        a1 += __shfl_down(a1, off);
    }
    if (l == 0) {
        float g0 = a0 + gb[0];
        float g1 = a1 + gb[1];
        geo[(size_t)row * 2 + 0] = g0;
        geo[(size_t)row * 2 + 1] = g1;
#pragma unroll
        for (int m = 0; m < 6; ++m)
            ro[(size_t)row * 6 + m] = g0 * rW[m * 2] + g1 * rW[m * 2 + 1];
    }
}

extern "C" void kernel_launch(void* const* d_in, const int* in_sizes, int n_in,
                              void* d_out, int out_size, void* d_ws, size_t ws_size,
                              hipStream_t stream) {
    const float* hidden0 = (const float*)d_in[0];
    const float* input   = (const float*)d_in[1];
    const float* lv      = (const float*)d_in[2];
    const float* rv      = (const float*)d_in[3];
    const float* noise   = (const float*)d_in[4];
    const float* gW      = (const float*)d_in[5];
    const float* gb      = (const float*)d_in[6];
    const float* rW      = (const float*)d_in[7];

    float* out_hidden = (float*)d_out;
    float* geo = out_hidden + (size_t)T_DIM * B_DIM * N_DIM;
    float* ro  = geo + (size_t)T_DIM * B_DIM * 2;

    unsigned short* wf    = (unsigned short*)d_ws;                  // 2 MB
    unsigned short* abuf0 = wf + (size_t)64 * 32 * 64 * 8;          // 128 KB
    unsigned short* abuf1 = abuf0 + (size_t)B_DIM * N_DIM;          // 128 KB
    unsigned* flags = (unsigned*)(abuf1 + (size_t)B_DIM * N_DIM);   // 512 B packed

    build_wf<<<2048, 64, 0, stream>>>(lv, rv, noise, wf, flags);

    void* args[] = { (void*)&hidden0, (void*)&input, (void*)&wf,
                     (void*)&out_hidden, (void*)&abuf0, (void*)&abuf1, (void*)&flags };
    hipError_t e = hipLaunchCooperativeKernel((const void*)rnn_recurrence,
                                              dim3(NBLK), dim3(256), args, 0, stream);
    if (e != hipSuccess) {
        // 32 blocks at this occupancy are trivially co-resident; the protocol
        // itself never requires cg — plain launch is a safe fallback.
        rnn_recurrence<<<dim3(NBLK), dim3(256), 0, stream>>>(
            hidden0, input, wf, out_hidden, abuf0, abuf1, flags);
    }

    geo_kernel<<<(T_DIM * B_DIM) / 4, 256, 0, stream>>>(out_hidden, gW, gb, rW, geo, ro);
}

// Round 11
// 2413.913 us; speedup vs baseline: 3.5504x; 1.0656x over previous
//
#include <hip/hip_runtime.h>
#include <hip/hip_bf16.h>

#define N_DIM 1024
#define R_DIM 6
#define B_DIM 64
#define T_DIM 400
#define NBLK 32

typedef short bf16x8 __attribute__((ext_vector_type(8)));
typedef float f32x4 __attribute__((ext_vector_type(4)));

__device__ inline unsigned short f2bf(float f) {
    unsigned int u = __float_as_uint(f);
    unsigned int r = (u + 0x7fffu + ((u >> 16) & 1u)) >> 16;
    return (unsigned short)r;
}

// Build W in MFMA B-fragment layout, bf16.
// WF[gg][s][lane][i] = W[16gg + (lane&15)][32s + (lane>>4)*8 + i]
// Block 0 zeroes the 4096-word mailbox array (4 bands x 32 consumers x 32
// producers), deterministic per launch.
__global__ void __launch_bounds__(64) build_wf(
    const float* __restrict__ lv,
    const float* __restrict__ rv,
    const float* __restrict__ noise,
    unsigned short* __restrict__ wf,
    unsigned* __restrict__ mbox)
{
    int blk = blockIdx.x;
    int l = threadIdx.x;
    if (blk == 0) {
#pragma unroll
        for (int k = 0; k < 64; ++k) mbox[k * 64 + l] = 0u;
    }
    int gg = blk >> 5;
    int s = blk & 31;
    int j = gg * 16 + (l & 15);
    int n0 = s * 32 + (l >> 4) * 8;
    unsigned short* dst = wf + ((size_t)blk * 64 + l) * 8;
    float rj[R_DIM];
#pragma unroll
    for (int k = 0; k < R_DIM; ++k) rj[k] = rv[k * N_DIM + j];
#pragma unroll
    for (int i = 0; i < 8; ++i) {
        int n = n0 + i;
        float acc = noise[j * N_DIM + n];
        float dot = 0.f;
#pragma unroll
        for (int k = 0; k < R_DIM; ++k) dot += rj[k] * lv[k * N_DIM + n];
        acc += dot * (1.0f / (float)N_DIM);
        dst[i] = f2bf(acc);
    }
}

// Publish one 16x16 tile slice: rows brow0..brow0+3, col jcol. Full-wave,
// non-atomic, write-through (sc0 sc1). Pair transpose (verified R6/R7/R9).
__device__ inline void publish_tile(unsigned short* dst, const float a[4],
                                    int brow0, int jcol, int l) {
    unsigned* d32 = (unsigned*)dst;
    int odd = l & 1;
    int j0 = jcol & ~1;
#pragma unroll
    for (int k = 0; k < 2; ++k) {
        float send = odd ? a[k] : a[k + 2];
        float got = __shfl_xor(send, 1);
        int row = brow0 + (odd ? (k + 2) : k);
        unsigned lo = odd ? f2bf(got)      : f2bf(a[k]);     // col j0
        unsigned hi = odd ? f2bf(a[k + 2]) : f2bf(got);      // col j0+1
        unsigned pk = lo | (hi << 16);
        unsigned* addr = d32 + ((row * N_DIM + j0) >> 1);
        asm volatile("global_store_dword %0, %1, off sc0 sc1"
                     :: "v"(addr), "v"(pk) : "memory");
    }
}

// Push this producer's step tag to all 32 consumers of its band:
// ONE lane-parallel store (lanes 0..31), each to a different consumer's
// PRIVATE mailbox line. mbox[w][consumer][producer].
__device__ inline void push_tag(unsigned* mbox, int w, int g, unsigned val, int l) {
    if (l < 32) {
        unsigned* addr = mbox + (w * 1024 + l * 32 + g);
        asm volatile("global_store_dword %0, %1, off sc0 sc1"
                     :: "v"(addr), "v"(val) : "memory");
    }
}

// Poll own private mailbox row: 32 dwords = 2 cachelines, read by this wave
// only (single-reader lines — no poller fan-in at the MALL).
__device__ inline void poll_mbox(const unsigned* myrow, unsigned target, int l) {
    const unsigned* p = myrow + (l & 31);
    for (;;) {
        unsigned v;
        asm volatile("global_load_dword %0, %1, off sc0 sc1\n\t"
                     "s_waitcnt vmcnt(0)"
                     : "=v"(v) : "v"(p) : "memory");
        if (__all(v >= target)) break;
        __builtin_amdgcn_s_sleep(1);
    }
}

// Coherent 16B load into av slot.
#define LOADA(slot, off)                                                       \
    asm volatile("global_load_dwordx4 %0, %1, off offset:" #off " sc0 sc1"     \
                 : "=v"(av[slot]) : "v"(ap) : "memory");

// One k-chunk s: A-fragment av[s] feeds both column tiles (nt=0,1).
#define MFMA_S(s, A0, A1)                                                      \
    A0 = __builtin_amdgcn_mfma_f32_16x16x32_bf16(av[s], wfrag[(s) * 64 + l],        A0, 0, 0, 0); \
    A1 = __builtin_amdgcn_mfma_f32_16x16x32_bf16(av[s], wfrag[(32 + (s)) * 64 + l], A1, 0, 0, 0);

// 32 blocks x 256 threads (cooperative, with plain-launch fallback).
// Block g owns jcols [32g,32g+32) (W slice 64 KB static LDS). Wave w = batch
// band [16w,16w+16). Bands are independent chains. Sync: private mailbox
// push (producer multicast) + single-reader poll. No barriers in the T-loop.
__global__ void __launch_bounds__(256, 1) rnn_recurrence(
    const float* __restrict__ hidden0,
    const float* __restrict__ input,        // [B][T][N]
    const unsigned short* __restrict__ wf,
    float* __restrict__ out_hidden,         // [T][B][N]
    unsigned short* __restrict__ abuf0,
    unsigned short* __restrict__ abuf1,
    unsigned* __restrict__ mbox)
{
    const int g = blockIdx.x;
    const int tid = threadIdx.x;
    const int w = tid >> 6;          // band
    const int l = tid & 63;
    const int brow0 = w * 16 + (l >> 4) * 4;

    // ---- stage this block's W slice (32 jcols = 64 KB) into LDS ----
    __shared__ __align__(16) unsigned short wlds[32 * 1024];
    {
        const bf16x8* src = reinterpret_cast<const bf16x8*>(wf) + (size_t)g * 4096;
        bf16x8* dstl = reinterpret_cast<bf16x8*>(wlds);
#pragma unroll
        for (int i = 0; i < 16; ++i)
            dstl[tid + i * 256] = src[tid + i * 256];
    }
    __syncthreads();
    const bf16x8* wfrag = reinterpret_cast<const bf16x8*>(wlds);

    int jc[2];
#pragma unroll
    for (int nt = 0; nt < 2; ++nt) jc[nt] = g * 32 + nt * 16 + (l & 15);

    // ---- init h & publish a0, push tag 1 ----
    float h[8];   // h[nt*4+i]
#pragma unroll
    for (int nt = 0; nt < 2; ++nt) {
        float h0v = hidden0[jc[nt]];
#pragma unroll
        for (int i = 0; i < 4; ++i) h[nt * 4 + i] = h0v;
    }
    {
        float a0[8];
#pragma unroll
        for (int k = 0; k < 8; ++k) a0[k] = tanhf(h[k]);
#pragma unroll
        for (int nt = 0; nt < 2; ++nt)
            publish_tile(abuf0, &a0[nt * 4], brow0, jc[nt], l);
        asm volatile("s_waitcnt vmcnt(0)" ::: "memory");
        push_tag(mbox, w, g, 1u, l);
    }

    const int aoff_us = (w * 16 + (l & 15)) * N_DIM + (l >> 4) * 8;
    const unsigned* myrow = mbox + (w * 1024 + g * 32);

    for (int t = 0; t < T_DIM; ++t) {
        const unsigned short* acur = (t & 1) ? abuf1 : abuf0;
        unsigned short* anext = (t & 1) ? abuf0 : abuf1;
        const unsigned short* ap = acur + aoff_us;

        // x loads issued before the poll (latency hidden under the wait;
        // the poll's vmcnt(0) drains them and prior stores)
        float x[8];
#pragma unroll
        for (int nt = 0; nt < 2; ++nt)
#pragma unroll
            for (int i = 0; i < 4; ++i)
                x[nt * 4 + i] = input[((size_t)(brow0 + i) * T_DIM + t) * N_DIM + jc[nt]];

        // wait until all 32 producers of this band pushed tag t+1
        poll_mbox(myrow, (unsigned)(t + 1), l);

        // ---- issue ALL 32 a-loads ----
        bf16x8 av[32];
        LOADA(0, 0)     LOADA(1, 64)    LOADA(2, 128)   LOADA(3, 192)
        LOADA(4, 256)   LOADA(5, 320)   LOADA(6, 384)   LOADA(7, 448)
        LOADA(8, 512)   LOADA(9, 576)   LOADA(10, 640)  LOADA(11, 704)
        LOADA(12, 768)  LOADA(13, 832)  LOADA(14, 896)  LOADA(15, 960)
        LOADA(16, 1024) LOADA(17, 1088) LOADA(18, 1152) LOADA(19, 1216)
        LOADA(20, 1280) LOADA(21, 1344) LOADA(22, 1408) LOADA(23, 1472)
        LOADA(24, 1536) LOADA(25, 1600) LOADA(26, 1664) LOADA(27, 1728)
        LOADA(28, 1792) LOADA(29, 1856) LOADA(30, 1920) LOADA(31, 1984)

        f32x4 a0e = {0.f, 0.f, 0.f, 0.f};
        f32x4 a0o = {0.f, 0.f, 0.f, 0.f};
        f32x4 a1e = {0.f, 0.f, 0.f, 0.f};
        f32x4 a1o = {0.f, 0.f, 0.f, 0.f};

        asm volatile("s_waitcnt vmcnt(24)" ::: "memory");   // a-loads 0..7 done
        __builtin_amdgcn_sched_barrier(0);
        MFMA_S(0, a0e, a1e) MFMA_S(1, a0o, a1o) MFMA_S(2, a0e, a1e) MFMA_S(3, a0o, a1o)
        MFMA_S(4, a0e, a1e) MFMA_S(5, a0o, a1o) MFMA_S(6, a0e, a1e) MFMA_S(7, a0o, a1o)
        asm volatile("s_waitcnt vmcnt(16)" ::: "memory");   // 8..15 done
        __builtin_amdgcn_sched_barrier(0);
        MFMA_S(8, a0e, a1e)  MFMA_S(9, a0o, a1o)  MFMA_S(10, a0e, a1e) MFMA_S(11, a0o, a1o)
        MFMA_S(12, a0e, a1e) MFMA_S(13, a0o, a1o) MFMA_S(14, a0e, a1e) MFMA_S(15, a0o, a1o)
        asm volatile("s_waitcnt vmcnt(8)" ::: "memory");    // 16..23 done
        __builtin_amdgcn_sched_barrier(0);
        MFMA_S(16, a0e, a1e) MFMA_S(17, a0o, a1o) MFMA_S(18, a0e, a1e) MFMA_S(19, a0o, a1o)
        MFMA_S(20, a0e, a1e) MFMA_S(21, a0o, a1o) MFMA_S(22, a0e, a1e) MFMA_S(23, a0o, a1o)
        asm volatile("s_waitcnt vmcnt(0)" ::: "memory");    // all done (incl. x)
        __builtin_amdgcn_sched_barrier(0);
        MFMA_S(24, a0e, a1e) MFMA_S(25, a0o, a1o) MFMA_S(26, a0e, a1e) MFMA_S(27, a0o, a1o)
        MFMA_S(28, a0e, a1e) MFMA_S(29, a0o, a1o) MFMA_S(30, a0e, a1e) MFMA_S(31, a0o, a1o)

        f32x4 acc0 = a0e + a0o;
        f32x4 acc1 = a1e + a1o;

        // ---- h update + activation ----
        float a[8];
#pragma unroll
        for (int i = 0; i < 4; ++i) {
            float hn;
            hn = 0.9f * h[0 + i] + 0.1f * (acc0[i] + x[0 + i]); h[0 + i] = hn; a[0 + i] = tanhf(hn);
            hn = 0.9f * h[4 + i] + 0.1f * (acc1[i] + x[4 + i]); h[4 + i] = hn; a[4 + i] = tanhf(hn);
        }

        if (t + 1 < T_DIM) {
#pragma unroll
            for (int nt = 0; nt < 2; ++nt)
                publish_tile(anext, &a[nt * 4], brow0, jc[nt], l);
            asm volatile("s_waitcnt vmcnt(0)" ::: "memory");   // publishes at MALL
            push_tag(mbox, w, g, (unsigned)(t + 2), l);
        }
        // out_hidden stores off the critical path (after tag push)
#pragma unroll
        for (int nt = 0; nt < 2; ++nt)
#pragma unroll
            for (int i = 0; i < 4; ++i)
                out_hidden[((size_t)t * B_DIM + (brow0 + i)) * N_DIM + jc[nt]] = a[nt * 4 + i];
    }
}

__global__ void __launch_bounds__(256) geo_kernel(
    const float* __restrict__ hid,
    const float* __restrict__ gW,
    const float* __restrict__ gb,
    const float* __restrict__ rW,
    float* __restrict__ geo,
    float* __restrict__ ro)
{
    int row = blockIdx.x * 4 + (threadIdx.x >> 6);
    int l = threadIdx.x & 63;
    const float* hrow = hid + (size_t)row * N_DIM;
    float a0 = 0.f, a1 = 0.f;
#pragma unroll
    for (int i = 0; i < N_DIM / 64; ++i) {
        int idx = i * 64 + l;
        float th = tanhf(hrow[idx]);
        a0 += th * gW[idx];
        a1 += th * gW[N_DIM + idx];
    }
#pragma unroll
    for (int off = 32; off; off >>= 1) {
        a0 += __shfl_down(a0, off);
        a1 += __shfl_down(a1, off);
    }
    if (l == 0) {
        float g0 = a0 + gb[0];
        float g1 = a1 + gb[1];
        geo[(size_t)row * 2 + 0] = g0;
        geo[(size_t)row * 2 + 1] = g1;
#pragma unroll
        for (int m = 0; m < 6; ++m)
            ro[(size_t)row * 6 + m] = g0 * rW[m * 2] + g1 * rW[m * 2 + 1];
    }
}

extern "C" void kernel_launch(void* const* d_in, const int* in_sizes, int n_in,
                              void* d_out, int out_size, void* d_ws, size_t ws_size,
                              hipStream_t stream) {
    const float* hidden0 = (const float*)d_in[0];
    const float* input   = (const float*)d_in[1];
    const float* lv      = (const float*)d_in[2];
    const float* rv      = (const float*)d_in[3];
    const float* noise   = (const float*)d_in[4];
    const float* gW      = (const float*)d_in[5];
    const float* gb      = (const float*)d_in[6];
    const float* rW      = (const float*)d_in[7];

    float* out_hidden = (float*)d_out;
    float* geo = out_hidden + (size_t)T_DIM * B_DIM * N_DIM;
    float* ro  = geo + (size_t)T_DIM * B_DIM * 2;

    unsigned short* wf    = (unsigned short*)d_ws;                  // 2 MB
    unsigned short* abuf0 = wf + (size_t)64 * 32 * 64 * 8;          // 128 KB
    unsigned short* abuf1 = abuf0 + (size_t)B_DIM * N_DIM;          // 128 KB
    unsigned* mbox = (unsigned*)(abuf1 + (size_t)B_DIM * N_DIM);    // 16 KB

    build_wf<<<2048, 64, 0, stream>>>(lv, rv, noise, wf, mbox);

    void* args[] = { (void*)&hidden0, (void*)&input, (void*)&wf,
                     (void*)&out_hidden, (void*)&abuf0, (void*)&abuf1, (void*)&mbox };
    hipError_t e = hipLaunchCooperativeKernel((const void*)rnn_recurrence,
                                              dim3(NBLK), dim3(256), args, 0, stream);
    if (e != hipSuccess) {
        // 32 blocks at this occupancy are trivially co-resident; the protocol
        // itself never requires cg — plain launch is a safe fallback.
        rnn_recurrence<<<dim3(NBLK), dim3(256), 0, stream>>>(
            hidden0, input, wf, out_hidden, abuf0, abuf1, mbox);
    }

    geo_kernel<<<(T_DIM * B_DIM) / 4, 256, 0, stream>>>(out_hidden, gW, gb, rW, geo, ro);
}